// Round 1
// 536.056 us; speedup vs baseline: 1.0763x; 1.0763x over previous
//
#include <hip/hip_runtime.h>

#define N_NODES 50000
#define N_EDGES 800000
#define N_GRAPHS 50
#define D 128
#define D_OUT 10
#define PLANE_F4 200000   // per-slice plane: 50000 nodes * 4 float4 (16 floats)

// ---------------------------------------------------------------------------
// 1) Degree histograms: cnt_dst (in-deg -> CSR row counts), cnt_src (out-deg)
// ---------------------------------------------------------------------------
__global__ __launch_bounds__(256) void hist_edges(const int* __restrict__ src,
                                                  const int* __restrict__ dst,
                                                  int* __restrict__ cnt_dst,
                                                  int* __restrict__ cnt_src) {
    int i = blockIdx.x * 256 + threadIdx.x;
    if (i < N_EDGES) {
        atomicAdd(&cnt_dst[dst[i]], 1);
        atomicAdd(&cnt_src[src[i]], 1);
    }
}

// ---------------------------------------------------------------------------
// 2) Single-block exclusive scan of cnt -> row_ptr; rewrites cnt as cursor.
// ---------------------------------------------------------------------------
__global__ __launch_bounds__(1024) void scan_k(int* __restrict__ cnt,
                                               int* __restrict__ row_ptr) {
    __shared__ int wsum[16];
    __shared__ int carry_s;
    int tid = threadIdx.x;
    int lane = tid & 63, wid = tid >> 6;
    if (tid == 0) carry_s = 0;
    __syncthreads();
    for (int base = 0; base < N_NODES; base += 4096) {
        int i0 = base + tid * 4;
        int v0 = (i0 + 0 < N_NODES) ? cnt[i0 + 0] : 0;
        int v1 = (i0 + 1 < N_NODES) ? cnt[i0 + 1] : 0;
        int v2 = (i0 + 2 < N_NODES) ? cnt[i0 + 2] : 0;
        int v3 = (i0 + 3 < N_NODES) ? cnt[i0 + 3] : 0;
        int s = v0 + v1 + v2 + v3;
        int x = s;
        #pragma unroll
        for (int d = 1; d < 64; d <<= 1) {
            int y = __shfl_up(x, d, 64);
            if (lane >= d) x += y;
        }
        if (lane == 63) wsum[wid] = x;
        __syncthreads();
        if (wid == 0) {
            int t = (lane < 16) ? wsum[lane] : 0;
            #pragma unroll
            for (int d = 1; d < 16; d <<= 1) {
                int y = __shfl_up(t, d, 64);
                if (lane >= d) t += y;
            }
            if (lane < 16) wsum[lane] = t;
        }
        __syncthreads();
        int woff = (wid == 0) ? 0 : wsum[wid - 1];
        int excl = carry_s + woff + (x - s);
        int run = excl;
        if (i0 + 0 < N_NODES) { row_ptr[i0 + 0] = run; cnt[i0 + 0] = run; } run += v0;
        if (i0 + 1 < N_NODES) { row_ptr[i0 + 1] = run; cnt[i0 + 1] = run; } run += v1;
        if (i0 + 2 < N_NODES) { row_ptr[i0 + 2] = run; cnt[i0 + 2] = run; } run += v2;
        if (i0 + 3 < N_NODES) { row_ptr[i0 + 3] = run; cnt[i0 + 3] = run; } run += v3;
        __syncthreads();
        if (tid == 0) carry_s += wsum[15];
        __syncthreads();
    }
    if (tid == 0) row_ptr[N_NODES] = carry_s;   // == N_EDGES
}

// ---------------------------------------------------------------------------
// 3) Norms: ns = clip(out_deg,1)^-0.5 ; nd = clip(in_deg,1)^-0.5
// ---------------------------------------------------------------------------
__global__ __launch_bounds__(256) void norms_k(const int* __restrict__ cnt_src,
                                               const int* __restrict__ row_ptr,
                                               float* __restrict__ ns,
                                               float* __restrict__ nd) {
    int v = blockIdx.x * 256 + threadIdx.x;
    if (v < N_NODES) {
        int od = cnt_src[v];
        int id = row_ptr[v + 1] - row_ptr[v];
        ns[v] = 1.0f / sqrtf((float)(od > 1 ? od : 1));
        nd[v] = 1.0f / sqrtf((float)(id > 1 ? id : 1));
    }
}

// ---------------------------------------------------------------------------
// 4) CSR scatter: col16[pos] = (ushort)src. N_NODES < 65536 so ushort fits;
//    halves the per-XCD col re-read in the sliced SpMM and the random
//    scatter-write bytes. "fill" is the scan-rewritten cnt buffer.
// ---------------------------------------------------------------------------
__global__ __launch_bounds__(256) void scatter_k(const int* __restrict__ src,
                                                 const int* __restrict__ dst,
                                                 int* __restrict__ fill,
                                                 unsigned short* __restrict__ col) {
    int i = blockIdx.x * 256 + threadIdx.x;
    if (i < N_EDGES) {
        int s = src[i];
        int d = dst[i];
        int p = atomicAdd(&fill[d], 1);
        col[p] = (unsigned short)s;
    }
}

// ---------------------------------------------------------------------------
// 5) Prescale + slice: xs[plane p][node][16] = ns[node] * h[node][p*16..+16].
//    Matches reference ordering: (h * norm_src) is rounded once, then gathered
//    and summed. Coalesced reads; 128B-segment writes per plane.
// ---------------------------------------------------------------------------
__global__ __launch_bounds__(256) void prescale_k(const float* __restrict__ h,
                                                  const float* __restrict__ ns,
                                                  float* __restrict__ out) {
    int i = blockIdx.x * 256 + threadIdx.x;      // over 1,600,000 float4s
    if (i < N_NODES * 32) {
        int node = i >> 5;
        int kg = i & 31;                          // float4 index within row
        float4 v = ((const float4*)h)[i];
        float s = ns[node];
        int p = kg >> 2, q = kg & 3;
        ((float4*)out)[p * PLANE_F4 + node * 4 + q] =
            make_float4(v.x * s, v.y * s, v.z * s, v.w * s);
    }
}

// ---------------------------------------------------------------------------
// 6) Feature-sliced SpMM: out[v, slice] = nd[v] * sum_e xs[col[e], slice].
//    slice = blockIdx.x & 7 -> lands on XCD (blockIdx % 8) under round-robin
//    dispatch, so each XCD's gather working set is ONE 3.2 MB plane that fits
//    its 4 MB L2 (vs 25.6 MB replicated 8x before). Slice-major storage means
//    no cache-line overfetch across slices. 4 lanes per node (float4 each),
//    64 nodes per 256-thread block, 4-edge unroll with 2 accumulators.
//    No weights: ns is pre-folded into xs by the producer.
// ---------------------------------------------------------------------------
__global__ __launch_bounds__(256) void spmm_k(const float* __restrict__ x,   // sliced
                                              const int* __restrict__ row_ptr,
                                              const unsigned short* __restrict__ col,
                                              const float* __restrict__ nd,
                                              float* __restrict__ out) {     // sliced
    int b = blockIdx.x;
    int slice = b & 7;                       // == XCD id under %8 round-robin
    int node = (b >> 3) * 64 + (threadIdx.x >> 2);
    if (node >= N_NODES) return;
    int q = threadIdx.x & 3;
    int s = row_ptr[node];
    int e = row_ptr[node + 1];
    const float4* xp = (const float4*)x + slice * PLANE_F4;
    float4 a0 = make_float4(0.f, 0.f, 0.f, 0.f);
    float4 a1 = make_float4(0.f, 0.f, 0.f, 0.f);
    int i = s;
    for (; i + 4 <= e; i += 4) {
        int c0 = col[i], c1 = col[i + 1], c2 = col[i + 2], c3 = col[i + 3];
        float4 h0 = xp[c0 * 4 + q];
        float4 h1 = xp[c1 * 4 + q];
        float4 h2 = xp[c2 * 4 + q];
        float4 h3 = xp[c3 * 4 + q];
        a0.x += h0.x; a0.y += h0.y; a0.z += h0.z; a0.w += h0.w;
        a1.x += h1.x; a1.y += h1.y; a1.z += h1.z; a1.w += h1.w;
        a0.x += h2.x; a0.y += h2.y; a0.z += h2.z; a0.w += h2.w;
        a1.x += h3.x; a1.y += h3.y; a1.z += h3.z; a1.w += h3.w;
    }
    for (; i < e; i++) {
        float4 hv = xp[col[i] * 4 + q];
        a0.x += hv.x; a0.y += hv.y; a0.z += hv.z; a0.w += hv.w;
    }
    float ndv = nd[node];
    ((float4*)out)[slice * PLANE_F4 + node * 4 + q] =
        make_float4((a0.x + a1.x) * ndv, (a0.y + a1.y) * ndv,
                    (a0.z + a1.z) * ndv, (a0.w + a1.w) * ndv);
}

// ---------------------------------------------------------------------------
// 7) GEMM + bias + ReLU, sliced A input. MODE 0: out = ns[row]*relu(A@W+b)
//    written SLICED (feeds next spmm). MODE 1: out = relu(A@W+b) written
//    NORMAL (feeds readout).
// ---------------------------------------------------------------------------
template <int MODE>
__global__ __launch_bounds__(256) void gemm_relu_k(const float* __restrict__ A,  // sliced
                                                   const float* __restrict__ W,
                                                   const float* __restrict__ bias,
                                                   const float* __restrict__ ns,
                                                   float* __restrict__ out) {
    __shared__ float As_t[128 * 64];   // [k][r]
    __shared__ float Ws[128 * 64];     // [k][c] (current 64-col half)
    int tid = threadIdx.x;
    int row0 = blockIdx.x * 64;
    const float4* A4 = (const float4*)A;

    #pragma unroll
    for (int it = 0; it < 8; it++) {
        int linear = it * 256 + tid;       // 0..2047
        int p = linear >> 8;               // plane 0..7
        int rem = linear & 255;
        int r = rem >> 2;                  // local row 0..63
        int q = rem & 3;                   // float4 within 16-float slice
        int row = row0 + r;
        float4 a = (row < N_NODES) ? A4[p * PLANE_F4 + row * 4 + q]
                                   : make_float4(0.f, 0.f, 0.f, 0.f);
        int kb = p * 16 + q * 4;
        As_t[(kb + 0) * 64 + r] = a.x;
        As_t[(kb + 1) * 64 + r] = a.y;
        As_t[(kb + 2) * 64 + r] = a.z;
        As_t[(kb + 3) * 64 + r] = a.w;
    }

    int cg = tid & 15;    // col group: c0 = cg*4 (within half)
    int rg = tid >> 4;    // 0..15   : r0 = rg*4
    float acc[2][4][4];
    #pragma unroll
    for (int h = 0; h < 2; h++)
        #pragma unroll
        for (int r = 0; r < 4; r++)
            #pragma unroll
            for (int c = 0; c < 4; c++) acc[h][r][c] = 0.f;

    for (int h = 0; h < 2; h++) {
        __syncthreads();
        #pragma unroll
        for (int it = 0; it < 8; it++) {
            int linear = it * 256 + tid;   // 0..2047 float4s
            int k = linear >> 4;
            int c4 = linear & 15;
            ((float4*)Ws)[linear] = ((const float4*)(W + k * 128 + h * 64))[c4];
        }
        __syncthreads();
        float (*ah)[4] = acc[h];
        for (int k = 0; k < 128; k++) {
            float4 av = *(const float4*)(As_t + k * 64 + rg * 4);
            float4 wv = *(const float4*)(Ws + k * 64 + cg * 4);
            ah[0][0] = fmaf(av.x, wv.x, ah[0][0]);
            ah[0][1] = fmaf(av.x, wv.y, ah[0][1]);
            ah[0][2] = fmaf(av.x, wv.z, ah[0][2]);
            ah[0][3] = fmaf(av.x, wv.w, ah[0][3]);
            ah[1][0] = fmaf(av.y, wv.x, ah[1][0]);
            ah[1][1] = fmaf(av.y, wv.y, ah[1][1]);
            ah[1][2] = fmaf(av.y, wv.z, ah[1][2]);
            ah[1][3] = fmaf(av.y, wv.w, ah[1][3]);
            ah[2][0] = fmaf(av.z, wv.x, ah[2][0]);
            ah[2][1] = fmaf(av.z, wv.y, ah[2][1]);
            ah[2][2] = fmaf(av.z, wv.z, ah[2][2]);
            ah[2][3] = fmaf(av.z, wv.w, ah[2][3]);
            ah[3][0] = fmaf(av.w, wv.x, ah[3][0]);
            ah[3][1] = fmaf(av.w, wv.y, ah[3][1]);
            ah[3][2] = fmaf(av.w, wv.z, ah[3][2]);
            ah[3][3] = fmaf(av.w, wv.w, ah[3][3]);
        }
    }

    #pragma unroll
    for (int h = 0; h < 2; h++) {
        float4 bv = ((const float4*)bias)[h * 16 + cg];
        #pragma unroll
        for (int r = 0; r < 4; r++) {
            int row = row0 + rg * 4 + r;
            if (row < N_NODES) {
                float4 o;
                o.x = fmaxf(acc[h][r][0] + bv.x, 0.f);
                o.y = fmaxf(acc[h][r][1] + bv.y, 0.f);
                o.z = fmaxf(acc[h][r][2] + bv.z, 0.f);
                o.w = fmaxf(acc[h][r][3] + bv.w, 0.f);
                if (MODE == 0) {
                    float s = ns[row];
                    o.x *= s; o.y *= s; o.z *= s; o.w *= s;
                    int p = h * 4 + (cg >> 2);
                    int q = cg & 3;
                    ((float4*)out)[p * PLANE_F4 + row * 4 + q] = o;
                } else {
                    ((float4*)out)[row * 32 + h * 16 + cg] = o;
                }
            }
        }
    }
}

// ---------------------------------------------------------------------------
// 8) Fused projection + readout (normal-layout input, unchanged).
// ---------------------------------------------------------------------------
__global__ __launch_bounds__(256) void proj_readout_k(const float* __restrict__ h,
                                                      const int* __restrict__ gid,
                                                      const float* __restrict__ Wm,
                                                      float* __restrict__ hgp,
                                                      int* __restrict__ gcnt) {
    __shared__ float Wmt[10 * 144];
    int tid = threadIdx.x;
    for (int i = tid; i < 1280; i += 256) {
        int k = i / 10, o = i % 10;
        Wmt[o * 144 + k + 4 * (k >> 5)] = Wm[i];
    }
    __syncthreads();

    int v = blockIdx.x * 64 + (tid >> 2);
    int quarter = tid & 3;
    int lane = tid & 63;

    float acc[D_OUT];
    #pragma unroll
    for (int o = 0; o < D_OUT; o++) acc[o] = 0.f;
    int g = -1;
    int cnt = 0;
    if (v < N_NODES) {
        g = gid[v];
        cnt = (quarter == 0) ? 1 : 0;
        const float4* h4 = (const float4*)h + v * 32 + quarter * 8;
        const float* wbase = Wmt + quarter * 36;
        #pragma unroll
        for (int kk = 0; kk < 8; kk++) {
            float4 hv = h4[kk];
            #pragma unroll
            for (int o = 0; o < D_OUT; o++) {
                float4 w = *(const float4*)(wbase + o * 144 + kk * 4);
                acc[o] += hv.x * w.x + hv.y * w.y + hv.z * w.z + hv.w * w.w;
            }
        }
    }

    #pragma unroll
    for (int d = 1; d < 64; d <<= 1) {
        int gp = __shfl_up(g, d, 64);
        int cp = __shfl_up(cnt, d, 64);
        bool take = (lane >= d) && (gp == g);
        #pragma unroll
        for (int o = 0; o < D_OUT; o++) {
            float ap = __shfl_up(acc[o], d, 64);
            if (take) acc[o] += ap;
        }
        if (take) cnt += cp;
    }
    int gn = __shfl_down(g, 1, 64);
    bool tail = (lane == 63) || (gn != g);
    if (tail && g >= 0) {
        #pragma unroll
        for (int o = 0; o < D_OUT; o++) atomicAdd(&hgp[g * D_OUT + o], acc[o]);
        if (cnt > 0) atomicAdd(&gcnt[g], cnt);
    }
}

// ---------------------------------------------------------------------------
// 9) Final: logits = hgp/cnt + bm ; log_softmax over axis 0 (graphs)
// ---------------------------------------------------------------------------
__global__ __launch_bounds__(512) void final_k(const float* __restrict__ hgp,
                                               const int* __restrict__ gcnt,
                                               const float* __restrict__ bm,
                                               float* __restrict__ out) {
    __shared__ float lg[N_GRAPHS * D_OUT];
    __shared__ float colm[D_OUT], colls[D_OUT];
    int tid = threadIdx.x;
    if (tid < N_GRAPHS * D_OUT) {
        int g = tid / D_OUT, o = tid % D_OUT;
        float c = (float)gcnt[g];
        lg[tid] = hgp[tid] / (c > 1.f ? c : 1.f) + bm[o];
    }
    __syncthreads();
    if (tid < D_OUT) {
        float m = -1e30f;
        for (int g = 0; g < N_GRAPHS; g++) m = fmaxf(m, lg[g * D_OUT + tid]);
        float s = 0.f;
        for (int g = 0; g < N_GRAPHS; g++) s += expf(lg[g * D_OUT + tid] - m);
        colm[tid] = m; colls[tid] = logf(s);
    }
    __syncthreads();
    if (tid < N_GRAPHS * D_OUT) {
        int o = tid % D_OUT;
        out[tid] = lg[tid] - colm[o] - colls[o];
    }
}

// ---------------------------------------------------------------------------
// Launch
// ---------------------------------------------------------------------------
extern "C" void kernel_launch(void* const* d_in, const int* in_sizes, int n_in,
                              void* d_out, int out_size, void* d_ws, size_t ws_size,
                              hipStream_t stream) {
    const float* h_in = (const float*)d_in[0];
    const int*   src  = (const int*)d_in[1];
    const int*   dst  = (const int*)d_in[2];
    const int*   gid  = (const int*)d_in[3];
    const float* W1 = (const float*)d_in[4];  const float* b1 = (const float*)d_in[5];
    const float* W2 = (const float*)d_in[6];  const float* b2 = (const float*)d_in[7];
    const float* W3 = (const float*)d_in[8];  const float* b3 = (const float*)d_in[9];
    const float* Wm = (const float*)d_in[10]; const float* bm = (const float*)d_in[11];

    char* ws = (char*)d_ws;
    // layout (all offsets 16B-aligned):
    int*            cnt     = (int*)(ws + 0);          // 50000 ints; becomes cursor
    int*            cnt_src = (int*)(ws + 200000);     // 50000 ints
    int*            gcnt    = (int*)(ws + 400000);     // 64 ints
    float*          hgp     = (float*)(ws + 400256);   // 500 floats (pad to 512)
    // zero region = [0, 402304)
    int*            row_ptr = (int*)(ws + 402304);     // 50001 ints (pad)
    unsigned short* col16   = (unsigned short*)(ws + 602320);  // 800000 ushort
    float*          ns      = (float*)(ws + 2202320);  // 50000 floats
    float*          nd      = (float*)(ws + 2402320);  // 50000 floats
    float*          bufA    = (float*)(ws + 2602320);  // 6.4M floats (sliced/normal)
    float*          bufB    = (float*)(ws + 28202320); // 6.4M floats (sliced)
    // total = 53,802,320 bytes

    hipMemsetAsync(ws, 0, 402304, stream);

    hist_edges<<<3125, 256, 0, stream>>>(src, dst, cnt, cnt_src);
    scan_k<<<1, 1024, 0, stream>>>(cnt, row_ptr);
    norms_k<<<196, 256, 0, stream>>>(cnt_src, row_ptr, ns, nd);
    scatter_k<<<3125, 256, 0, stream>>>(src, dst, cnt, col16);
    prescale_k<<<6250, 256, 0, stream>>>(h_in, ns, bufA);

    spmm_k<<<6256, 256, 0, stream>>>(bufA, row_ptr, col16, nd, bufB);
    gemm_relu_k<0><<<782, 256, 0, stream>>>(bufB, W1, b1, ns, bufA);
    spmm_k<<<6256, 256, 0, stream>>>(bufA, row_ptr, col16, nd, bufB);
    gemm_relu_k<0><<<782, 256, 0, stream>>>(bufB, W2, b2, ns, bufA);
    spmm_k<<<6256, 256, 0, stream>>>(bufA, row_ptr, col16, nd, bufB);
    gemm_relu_k<1><<<782, 256, 0, stream>>>(bufB, W3, b3, ns, bufA);

    proj_readout_k<<<782, 256, 0, stream>>>(bufA, gid, Wm, hgp, gcnt);
    final_k<<<1, 512, 0, stream>>>(hgp, gcnt, bm, (float*)d_out);
}

// Round 2
// 523.242 us; speedup vs baseline: 1.1027x; 1.0245x over previous
//
#include <hip/hip_runtime.h>

#define N_NODES 50000
#define N_EDGES 800000
#define N_GRAPHS 50
#define D 128
#define D_OUT 10
#define PLANE_F4 200000   // per-slice plane: 50000 nodes * 4 float4 (16 floats)
#define NSH 8             // histogram shards (one per XCD)

// ---------------------------------------------------------------------------
// 1) XCD-sharded degree histograms. shard = blockIdx&7 -> under round-robin
//    dispatch each 200KB shard is only ever touched by ONE XCD, so the
//    atomic's cache line never becomes cross-XCD shared (test: if agent-scope
//    atomics can then execute L2-side, WRITE_SIZE collapses 49.8MB -> ~0).
//    Fire-and-forget (no return value used).
// ---------------------------------------------------------------------------
__global__ __launch_bounds__(256) void hist8_k(const int* __restrict__ src,
                                               const int* __restrict__ dst,
                                               int* __restrict__ cnt8,
                                               int* __restrict__ cs8) {
    int i = blockIdx.x * 256 + threadIdx.x;
    int sh = (blockIdx.x & (NSH - 1)) * N_NODES;
    if (i < N_EDGES) {
        atomicAdd(&cnt8[sh + dst[i]], 1);
        atomicAdd(&cs8[sh + src[i]], 1);
    }
}

// ---------------------------------------------------------------------------
// 2a) scanA: per-block (196 nodes) sum of 8-shard in-degree -> bs[block]
// ---------------------------------------------------------------------------
__global__ __launch_bounds__(256) void scanA_k(const int* __restrict__ cnt8,
                                               int* __restrict__ bs) {
    int b = blockIdx.x, t = threadIdx.x;
    int n = b * 196 + t;
    int v = 0;
    if (t < 196 && n < N_NODES) {
        #pragma unroll
        for (int x = 0; x < NSH; x++) v += cnt8[x * N_NODES + n];
    }
    __shared__ int wsum[4];
    int lane = t & 63, wid = t >> 6;
    #pragma unroll
    for (int d = 32; d; d >>= 1) v += __shfl_down(v, d, 64);
    if (lane == 0) wsum[wid] = v;
    __syncthreads();
    if (t == 0) bs[b] = wsum[0] + wsum[1] + wsum[2] + wsum[3];
}

// ---------------------------------------------------------------------------
// 2b) scanB: single-block exclusive scan of bs[256] in place.
// ---------------------------------------------------------------------------
__global__ __launch_bounds__(256) void scanB_k(int* __restrict__ bs) {
    int t = threadIdx.x;
    int v = bs[t];
    int lane = t & 63, wid = t >> 6;
    __shared__ int wsum[4];
    int x = v;
    #pragma unroll
    for (int d = 1; d < 64; d <<= 1) {
        int y = __shfl_up(x, d, 64);
        if (lane >= d) x += y;
    }
    if (lane == 63) wsum[wid] = x;
    __syncthreads();
    int add = 0;
    #pragma unroll
    for (int i = 0; i < 4; i++) if (i < wid) add += wsum[i];
    bs[t] = add + x - v;          // exclusive
}

// ---------------------------------------------------------------------------
// 2c) scanC: per node -> row_ptr, per-(node,shard) cursor base (written back
//     into cnt8 in place), and both norms (replaces norms_k).
// ---------------------------------------------------------------------------
__global__ __launch_bounds__(256) void scanC_k(int* __restrict__ cnt8,      // -> cursor8
                                               const int* __restrict__ cs8,
                                               const int* __restrict__ bs,
                                               int* __restrict__ row_ptr,
                                               float* __restrict__ ns,
                                               float* __restrict__ nd) {
    int b = blockIdx.x, t = threadIdx.x;
    int n = b * 196 + t;
    bool act = (t < 196) && (n < N_NODES);
    int c[NSH];
    int v = 0;
    if (act) {
        #pragma unroll
        for (int x = 0; x < NSH; x++) { c[x] = cnt8[x * N_NODES + n]; v += c[x]; }
    }
    int lane = t & 63, wid = t >> 6;
    __shared__ int wsum[4];
    int xv = v;
    #pragma unroll
    for (int d = 1; d < 64; d <<= 1) {
        int y = __shfl_up(xv, d, 64);
        if (lane >= d) xv += y;
    }
    if (lane == 63) wsum[wid] = xv;
    __syncthreads();
    int add = 0;
    #pragma unroll
    for (int i = 0; i < 4; i++) if (i < wid) add += wsum[i];
    int excl = bs[b] + add + xv - v;
    if (act) {
        row_ptr[n] = excl;
        int rb = excl;
        #pragma unroll
        for (int x = 0; x < NSH; x++) { cnt8[x * N_NODES + n] = rb; rb += c[x]; }
        int od = 0;
        #pragma unroll
        for (int x = 0; x < NSH; x++) od += cs8[x * N_NODES + n];
        ns[n] = 1.0f / sqrtf((float)(od > 1 ? od : 1));
        nd[n] = 1.0f / sqrtf((float)(v > 1 ? v : 1));
    }
    if (b == 255 && t == 0) row_ptr[N_NODES] = N_EDGES;
}

// ---------------------------------------------------------------------------
// 3) Sharded CSR scatter: cursor shard matches hist8's (same grid shape ->
//    same blockIdx&7 per edge, so per-shard capacities line up exactly).
// ---------------------------------------------------------------------------
__global__ __launch_bounds__(256) void scatter8_k(const int* __restrict__ src,
                                                  const int* __restrict__ dst,
                                                  int* __restrict__ cursor8,
                                                  unsigned short* __restrict__ col) {
    int i = blockIdx.x * 256 + threadIdx.x;
    int sh = (blockIdx.x & (NSH - 1)) * N_NODES;
    if (i < N_EDGES) {
        int s = src[i];
        int d = dst[i];
        int p = atomicAdd(&cursor8[sh + d], 1);
        col[p] = (unsigned short)s;
    }
}

// ---------------------------------------------------------------------------
// 4) Prescale + slice: xs[plane p][node][16] = ns[node] * h[node][p*16..+16].
// ---------------------------------------------------------------------------
__global__ __launch_bounds__(256) void prescale_k(const float* __restrict__ h,
                                                  const float* __restrict__ ns,
                                                  float* __restrict__ out) {
    int i = blockIdx.x * 256 + threadIdx.x;      // over 1,600,000 float4s
    if (i < N_NODES * 32) {
        int node = i >> 5;
        int kg = i & 31;
        float4 v = ((const float4*)h)[i];
        float s = ns[node];
        int p = kg >> 2, q = kg & 3;
        ((float4*)out)[p * PLANE_F4 + node * 4 + q] =
            make_float4(v.x * s, v.y * s, v.z * s, v.w * s);
    }
}

// ---------------------------------------------------------------------------
// 5) Feature-sliced SpMM (unchanged from last round -- it worked).
// ---------------------------------------------------------------------------
__global__ __launch_bounds__(256) void spmm_k(const float* __restrict__ x,   // sliced
                                              const int* __restrict__ row_ptr,
                                              const unsigned short* __restrict__ col,
                                              const float* __restrict__ nd,
                                              float* __restrict__ out) {     // sliced
    int b = blockIdx.x;
    int slice = b & 7;
    int node = (b >> 3) * 64 + (threadIdx.x >> 2);
    if (node >= N_NODES) return;
    int q = threadIdx.x & 3;
    int s = row_ptr[node];
    int e = row_ptr[node + 1];
    const float4* xp = (const float4*)x + slice * PLANE_F4;
    float4 a0 = make_float4(0.f, 0.f, 0.f, 0.f);
    float4 a1 = make_float4(0.f, 0.f, 0.f, 0.f);
    int i = s;
    for (; i + 4 <= e; i += 4) {
        int c0 = col[i], c1 = col[i + 1], c2 = col[i + 2], c3 = col[i + 3];
        float4 h0 = xp[c0 * 4 + q];
        float4 h1 = xp[c1 * 4 + q];
        float4 h2 = xp[c2 * 4 + q];
        float4 h3 = xp[c3 * 4 + q];
        a0.x += h0.x; a0.y += h0.y; a0.z += h0.z; a0.w += h0.w;
        a1.x += h1.x; a1.y += h1.y; a1.z += h1.z; a1.w += h1.w;
        a0.x += h2.x; a0.y += h2.y; a0.z += h2.z; a0.w += h2.w;
        a1.x += h3.x; a1.y += h3.y; a1.z += h3.z; a1.w += h3.w;
    }
    for (; i < e; i++) {
        float4 hv = xp[col[i] * 4 + q];
        a0.x += hv.x; a0.y += hv.y; a0.z += hv.z; a0.w += hv.w;
    }
    float ndv = nd[node];
    ((float4*)out)[slice * PLANE_F4 + node * 4 + q] =
        make_float4((a0.x + a1.x) * ndv, (a0.y + a1.y) * ndv,
                    (a0.z + a1.z) * ndv, (a0.w + a1.w) * ndv);
}

// ---------------------------------------------------------------------------
// 6) GEMM + bias + ReLU, rebalanced: 256x128 tile, 512 threads, 8x8 per-thread
//    tile. A in 128KB LDS ([k][r], b128 reads mostly broadcast); W streamed
//    from global (64KB, L2-resident; moves W reads off the LDS pipe).
//    MODE 0: out = ns[row]*relu(A@W+b) written SLICED. MODE 1: normal layout.
// ---------------------------------------------------------------------------
template <int MODE>
__global__ __launch_bounds__(512) void gemm_relu_k(const float* __restrict__ A,  // sliced
                                                   const float* __restrict__ W,
                                                   const float* __restrict__ bias,
                                                   const float* __restrict__ ns,
                                                   float* __restrict__ out) {
    __shared__ float As_t[128 * 256];   // 128 KB: [k][r]
    int tid = threadIdx.x;
    int row0 = blockIdx.x * 256;
    const float4* A4 = (const float4*)A;

    #pragma unroll
    for (int it = 0; it < 16; it++) {
        int linear = it * 512 + tid;       // 0..8191 float4s
        int p = linear >> 10;              // plane 0..7
        int rem = linear & 1023;
        int r = rem >> 2;                  // local row 0..255
        int q = rem & 3;                   // float4 within 16-float slice
        int row = row0 + r;
        float4 a = (row < N_NODES) ? A4[p * PLANE_F4 + row * 4 + q]
                                   : make_float4(0.f, 0.f, 0.f, 0.f);
        int kb = p * 16 + q * 4;
        As_t[(kb + 0) * 256 + r] = a.x;
        As_t[(kb + 1) * 256 + r] = a.y;
        As_t[(kb + 2) * 256 + r] = a.z;
        As_t[(kb + 3) * 256 + r] = a.w;
    }
    __syncthreads();

    int tc = tid & 15;    // col group: cols tc*8 .. +8
    int tr = tid >> 4;    // 0..31 : rows tr*8 .. +8
    float acc[8][8];
    #pragma unroll
    for (int r = 0; r < 8; r++)
        #pragma unroll
        for (int c = 0; c < 8; c++) acc[r][c] = 0.f;

    const float4* W4 = (const float4*)W;
    #pragma unroll 2
    for (int k = 0; k < 128; k++) {
        float4 w0 = W4[k * 32 + tc * 2];
        float4 w1 = W4[k * 32 + tc * 2 + 1];
        float4 a0 = *(const float4*)(As_t + k * 256 + tr * 8);
        float4 a1 = *(const float4*)(As_t + k * 256 + tr * 8 + 4);
        float av[8] = {a0.x, a0.y, a0.z, a0.w, a1.x, a1.y, a1.z, a1.w};
        float wv[8] = {w0.x, w0.y, w0.z, w0.w, w1.x, w1.y, w1.z, w1.w};
        #pragma unroll
        for (int rr = 0; rr < 8; rr++)
            #pragma unroll
            for (int cc = 0; cc < 8; cc++)
                acc[rr][cc] = fmaf(av[rr], wv[cc], acc[rr][cc]);
    }

    float4 bv0 = ((const float4*)bias)[tc * 2];
    float4 bv1 = ((const float4*)bias)[tc * 2 + 1];
    #pragma unroll
    for (int rr = 0; rr < 8; rr++) {
        int row = row0 + tr * 8 + rr;
        if (row < N_NODES) {
            float4 o0, o1;
            o0.x = fmaxf(acc[rr][0] + bv0.x, 0.f);
            o0.y = fmaxf(acc[rr][1] + bv0.y, 0.f);
            o0.z = fmaxf(acc[rr][2] + bv0.z, 0.f);
            o0.w = fmaxf(acc[rr][3] + bv0.w, 0.f);
            o1.x = fmaxf(acc[rr][4] + bv1.x, 0.f);
            o1.y = fmaxf(acc[rr][5] + bv1.y, 0.f);
            o1.z = fmaxf(acc[rr][6] + bv1.z, 0.f);
            o1.w = fmaxf(acc[rr][7] + bv1.w, 0.f);
            if (MODE == 0) {
                float s = ns[row];
                o0.x *= s; o0.y *= s; o0.z *= s; o0.w *= s;
                o1.x *= s; o1.y *= s; o1.z *= s; o1.w *= s;
                int p = tc >> 1;
                int q0 = (tc & 1) * 2;
                ((float4*)out)[p * PLANE_F4 + row * 4 + q0] = o0;
                ((float4*)out)[p * PLANE_F4 + row * 4 + q0 + 1] = o1;
            } else {
                ((float4*)out)[row * 32 + tc * 2] = o0;
                ((float4*)out)[row * 32 + tc * 2 + 1] = o1;
            }
        }
    }
}

// ---------------------------------------------------------------------------
// 7) Fused projection + readout (normal-layout input, unchanged).
// ---------------------------------------------------------------------------
__global__ __launch_bounds__(256) void proj_readout_k(const float* __restrict__ h,
                                                      const int* __restrict__ gid,
                                                      const float* __restrict__ Wm,
                                                      float* __restrict__ hgp,
                                                      int* __restrict__ gcnt) {
    __shared__ float Wmt[10 * 144];
    int tid = threadIdx.x;
    for (int i = tid; i < 1280; i += 256) {
        int k = i / 10, o = i % 10;
        Wmt[o * 144 + k + 4 * (k >> 5)] = Wm[i];
    }
    __syncthreads();

    int v = blockIdx.x * 64 + (tid >> 2);
    int quarter = tid & 3;
    int lane = tid & 63;

    float acc[D_OUT];
    #pragma unroll
    for (int o = 0; o < D_OUT; o++) acc[o] = 0.f;
    int g = -1;
    int cnt = 0;
    if (v < N_NODES) {
        g = gid[v];
        cnt = (quarter == 0) ? 1 : 0;
        const float4* h4 = (const float4*)h + v * 32 + quarter * 8;
        const float* wbase = Wmt + quarter * 36;
        #pragma unroll
        for (int kk = 0; kk < 8; kk++) {
            float4 hv = h4[kk];
            #pragma unroll
            for (int o = 0; o < D_OUT; o++) {
                float4 w = *(const float4*)(wbase + o * 144 + kk * 4);
                acc[o] += hv.x * w.x + hv.y * w.y + hv.z * w.z + hv.w * w.w;
            }
        }
    }

    #pragma unroll
    for (int d = 1; d < 64; d <<= 1) {
        int gp = __shfl_up(g, d, 64);
        int cp = __shfl_up(cnt, d, 64);
        bool take = (lane >= d) && (gp == g);
        #pragma unroll
        for (int o = 0; o < D_OUT; o++) {
            float ap = __shfl_up(acc[o], d, 64);
            if (take) acc[o] += ap;
        }
        if (take) cnt += cp;
    }
    int gn = __shfl_down(g, 1, 64);
    bool tail = (lane == 63) || (gn != g);
    if (tail && g >= 0) {
        #pragma unroll
        for (int o = 0; o < D_OUT; o++) atomicAdd(&hgp[g * D_OUT + o], acc[o]);
        if (cnt > 0) atomicAdd(&gcnt[g], cnt);
    }
}

// ---------------------------------------------------------------------------
// 8) Final: logits = hgp/cnt + bm ; log_softmax over axis 0 (graphs)
// ---------------------------------------------------------------------------
__global__ __launch_bounds__(512) void final_k(const float* __restrict__ hgp,
                                               const int* __restrict__ gcnt,
                                               const float* __restrict__ bm,
                                               float* __restrict__ out) {
    __shared__ float lg[N_GRAPHS * D_OUT];
    __shared__ float colm[D_OUT], colls[D_OUT];
    int tid = threadIdx.x;
    if (tid < N_GRAPHS * D_OUT) {
        int g = tid / D_OUT, o = tid % D_OUT;
        float c = (float)gcnt[g];
        lg[tid] = hgp[tid] / (c > 1.f ? c : 1.f) + bm[o];
    }
    __syncthreads();
    if (tid < D_OUT) {
        float m = -1e30f;
        for (int g = 0; g < N_GRAPHS; g++) m = fmaxf(m, lg[g * D_OUT + tid]);
        float s = 0.f;
        for (int g = 0; g < N_GRAPHS; g++) s += expf(lg[g * D_OUT + tid] - m);
        colm[tid] = m; colls[tid] = logf(s);
    }
    __syncthreads();
    if (tid < N_GRAPHS * D_OUT) {
        int o = tid % D_OUT;
        out[tid] = lg[tid] - colm[o] - colls[o];
    }
}

// ---------------------------------------------------------------------------
// Launch. Workspace overlays: cnt8 (dead after scatter8) aliases bufA, which
// is first written by prescale_k (launched after scatter8); cs8 (dead after
// scanC) aliases bufB, first written by spmm #1. Total footprint 53.4 MB.
// ---------------------------------------------------------------------------
extern "C" void kernel_launch(void* const* d_in, const int* in_sizes, int n_in,
                              void* d_out, int out_size, void* d_ws, size_t ws_size,
                              hipStream_t stream) {
    const float* h_in = (const float*)d_in[0];
    const int*   src  = (const int*)d_in[1];
    const int*   dst  = (const int*)d_in[2];
    const int*   gid  = (const int*)d_in[3];
    const float* W1 = (const float*)d_in[4];  const float* b1 = (const float*)d_in[5];
    const float* W2 = (const float*)d_in[6];  const float* b2 = (const float*)d_in[7];
    const float* W3 = (const float*)d_in[8];  const float* b3 = (const float*)d_in[9];
    const float* Wm = (const float*)d_in[10]; const float* bm = (const float*)d_in[11];

    char* ws = (char*)d_ws;
    int*            row_ptr = (int*)(ws + 0);                     // 50001 ints (pad 200,032)
    unsigned short* col16   = (unsigned short*)(ws + 200032);     // 1,600,000 B
    float*          ns      = (float*)(ws + 1800032);             // 200,000 B
    float*          nd      = (float*)(ws + 2000032);             // 200,000 B
    int*            gcnt    = (int*)(ws + 2200032);               // 256 B
    float*          hgp     = (float*)(ws + 2200288);             // 2,048 B
    int*            bs      = (int*)(ws + 2202336);               // 1,024 B
    float*          bufA    = (float*)(ws + 2203360);             // 25.6 MB
    float*          bufB    = (float*)(ws + 27803360);            // 25.6 MB -> 53,403,360
    int*            cnt8    = (int*)bufA;                         // 1.6 MB alias
    int*            cs8     = (int*)bufB;                         // 1.6 MB alias

    hipMemsetAsync(ws + 2200032, 0, 2304, stream);      // gcnt + hgp
    hipMemsetAsync(cnt8, 0, 1600000, stream);
    hipMemsetAsync(cs8, 0, 1600000, stream);

    hist8_k<<<3125, 256, 0, stream>>>(src, dst, cnt8, cs8);
    scanA_k<<<256, 256, 0, stream>>>(cnt8, bs);
    scanB_k<<<1, 256, 0, stream>>>(bs);
    scanC_k<<<256, 256, 0, stream>>>(cnt8, cs8, bs, row_ptr, ns, nd);
    scatter8_k<<<3125, 256, 0, stream>>>(src, dst, cnt8, col16);
    prescale_k<<<6250, 256, 0, stream>>>(h_in, ns, bufA);   // overwrites cnt8 region (dead)

    spmm_k<<<6256, 256, 0, stream>>>(bufA, row_ptr, col16, nd, bufB);
    gemm_relu_k<0><<<196, 512, 0, stream>>>(bufB, W1, b1, ns, bufA);
    spmm_k<<<6256, 256, 0, stream>>>(bufA, row_ptr, col16, nd, bufB);
    gemm_relu_k<0><<<196, 512, 0, stream>>>(bufB, W2, b2, ns, bufA);
    spmm_k<<<6256, 256, 0, stream>>>(bufA, row_ptr, col16, nd, bufB);
    gemm_relu_k<1><<<196, 512, 0, stream>>>(bufB, W3, b3, ns, bufA);

    proj_readout_k<<<782, 256, 0, stream>>>(bufA, gid, Wm, hgp, gcnt);
    final_k<<<1, 512, 0, stream>>>(hgp, gcnt, bm, (float*)d_out);
}

// Round 3
// 474.410 us; speedup vs baseline: 1.2162x; 1.1029x over previous
//
#include <hip/hip_runtime.h>

#define N_NODES 50000
#define N_EDGES 800000
#define N_GRAPHS 50
#define D 128
#define D_OUT 10
#define PLANE_F4 200000   // per-slice plane: 50000 nodes * 4 float4 (16 floats)
#define NB 196            // coarse buckets: dst>>8 (49999>>8 == 195)
#define NBLK 196          // partition blocks (196*4096 >= 800000)

// ---------------------------------------------------------------------------
// 1) Coarse partition histogram (LDS, no device atomics for dst) + src
//    out-degree histogram (the one unavoidable device-atomic stream).
//    gh layout: [bucket][block] (bucket-major) for the partition scan.
// ---------------------------------------------------------------------------
__global__ __launch_bounds__(256) void part_hist_src(const int* __restrict__ src,
                                                     const int* __restrict__ dst,
                                                     int* __restrict__ gh,
                                                     int* __restrict__ out_deg) {
    __shared__ int lh[NB];
    int tid = threadIdx.x, blk = blockIdx.x;
    if (tid < NB) lh[tid] = 0;
    __syncthreads();
    int base = blk * 4096;
    #pragma unroll
    for (int j = 0; j < 16; j++) {
        int i = base + j * 256 + tid;
        if (i < N_EDGES) {
            atomicAdd(&out_deg[src[i]], 1);          // device atomic (src stream)
            atomicAdd(&lh[dst[i] >> 8], 1);          // LDS atomic (dst stream)
        }
    }
    __syncthreads();
    if (tid < NB) gh[tid * NBLK + blk] = lh[tid];
}

// ---------------------------------------------------------------------------
// 2) Single-block exclusive scan of gh[NB*NBLK = 38416] in place.
//    Each entry becomes the global base for (bucket, block).
// ---------------------------------------------------------------------------
__global__ __launch_bounds__(1024) void part_scan(int* __restrict__ gh) {
    __shared__ int wsum[16];
    __shared__ int carry_s;
    const int N = NB * NBLK;            // 38416
    int tid = threadIdx.x;
    int lane = tid & 63, wid = tid >> 6;
    if (tid == 0) carry_s = 0;
    __syncthreads();
    for (int base = 0; base < N; base += 4096) {
        int i0 = base + tid * 4;
        int v0 = (i0 + 0 < N) ? gh[i0 + 0] : 0;
        int v1 = (i0 + 1 < N) ? gh[i0 + 1] : 0;
        int v2 = (i0 + 2 < N) ? gh[i0 + 2] : 0;
        int v3 = (i0 + 3 < N) ? gh[i0 + 3] : 0;
        int s = v0 + v1 + v2 + v3;
        int x = s;
        #pragma unroll
        for (int d = 1; d < 64; d <<= 1) {
            int y = __shfl_up(x, d, 64);
            if (lane >= d) x += y;
        }
        if (lane == 63) wsum[wid] = x;
        __syncthreads();
        if (wid == 0) {
            int t = (lane < 16) ? wsum[lane] : 0;
            #pragma unroll
            for (int d = 1; d < 16; d <<= 1) {
                int y = __shfl_up(t, d, 64);
                if (lane >= d) t += y;
            }
            if (lane < 16) wsum[lane] = t;
        }
        __syncthreads();
        int woff = (wid == 0) ? 0 : wsum[wid - 1];
        int run = carry_s + woff + (x - s);
        if (i0 + 0 < N) gh[i0 + 0] = run; run += v0;
        if (i0 + 1 < N) gh[i0 + 1] = run; run += v1;
        if (i0 + 2 < N) gh[i0 + 2] = run; run += v2;
        if (i0 + 3 < N) gh[i0 + 3] = run; run += v3;
        __syncthreads();
        if (tid == 0) carry_s += wsum[15];
        __syncthreads();
    }
}

// ---------------------------------------------------------------------------
// 3) Partition scatter: LDS cursors (shared-memory atomics only). Writes
//    packed ((dst&255)<<16)|src into the coarse-bucket-partitioned array.
// ---------------------------------------------------------------------------
__global__ __launch_bounds__(256) void part_scatter(const int* __restrict__ src,
                                                    const int* __restrict__ dst,
                                                    const int* __restrict__ gh,
                                                    unsigned int* __restrict__ packed) {
    __shared__ int lc[NB];
    int tid = threadIdx.x, blk = blockIdx.x;
    if (tid < NB) lc[tid] = gh[tid * NBLK + blk];
    __syncthreads();
    int base = blk * 4096;
    #pragma unroll
    for (int j = 0; j < 16; j++) {
        int i = base + j * 256 + tid;
        if (i < N_EDGES) {
            int d = dst[i];
            int s = src[i];
            int p = atomicAdd(&lc[d >> 8], 1);       // LDS atomic
            packed[p] = ((unsigned int)(d & 255) << 16) | (unsigned int)s;
        }
    }
}

// ---------------------------------------------------------------------------
// 4) Per-bucket CSR build: one block per coarse bucket (~4096 edges, <=8192).
//    LDS-staged: 256-bin hist -> block scan -> row_ptr + nd + in-LDS column
//    ordering, dumped as fully coalesced col16. No device atomics.
// ---------------------------------------------------------------------------
__global__ __launch_bounds__(256) void bucket_csr(const unsigned int* __restrict__ packed,
                                                  const int* __restrict__ gh,
                                                  unsigned short* __restrict__ col16,
                                                  int* __restrict__ row_ptr,
                                                  float* __restrict__ nd) {
    __shared__ unsigned int ep[8192];
    __shared__ unsigned short lcol[8192];
    __shared__ int hist[256], cur[256], wsum[4];
    int t = threadIdx.x, b = blockIdx.x;
    int nb = gh[b * NBLK];
    int ne = (b < NB - 1) ? gh[(b + 1) * NBLK] : N_EDGES;
    int cnt = ne - nb;
    if (cnt > 8192) cnt = 8192;         // statistically unreachable guard
    hist[t] = 0;
    __syncthreads();
    for (int i = t; i < cnt; i += 256) {
        unsigned int e = packed[nb + i];
        ep[i] = e;
        atomicAdd(&hist[e >> 16], 1);
    }
    __syncthreads();
    // block-exclusive scan of hist[256]
    int v = hist[t];
    int lane = t & 63, w = t >> 6;
    int x = v;
    #pragma unroll
    for (int d = 1; d < 64; d <<= 1) {
        int y = __shfl_up(x, d, 64);
        if (lane >= d) x += y;
    }
    if (lane == 63) wsum[w] = x;
    __syncthreads();
    int add = 0;
    #pragma unroll
    for (int i = 0; i < 4; i++) if (i < w) add += wsum[i];
    int excl = add + x - v;
    cur[t] = excl;
    int node = b * 256 + t;
    if (node < N_NODES) {
        row_ptr[node] = nb + excl;
        int id = v > 1 ? v : 1;
        nd[node] = 1.0f / sqrtf((float)id);
    }
    if (b == NB - 1 && t == 0) row_ptr[N_NODES] = N_EDGES;
    __syncthreads();
    for (int i = t; i < cnt; i += 256) {
        unsigned int e = ep[i];
        int p = atomicAdd(&cur[e >> 16], 1);         // LDS atomic
        lcol[p] = (unsigned short)(e & 0xFFFF);
    }
    __syncthreads();
    for (int i = t; i < cnt; i += 256) col16[nb + i] = lcol[i];
}

// ---------------------------------------------------------------------------
// 5) Prescale + slice: xs[p][node][16] = out_deg[node]^-1/2 * h[node][p*16..].
// ---------------------------------------------------------------------------
__global__ __launch_bounds__(256) void prescale_k(const float* __restrict__ h,
                                                  const int* __restrict__ out_deg,
                                                  float* __restrict__ out) {
    int i = blockIdx.x * 256 + threadIdx.x;      // over 1,600,000 float4s
    if (i < N_NODES * 32) {
        int node = i >> 5;
        int kg = i & 31;
        float4 v = ((const float4*)h)[i];
        int od = out_deg[node];
        float s = 1.0f / sqrtf((float)(od > 1 ? od : 1));
        int p = kg >> 2, q = kg & 3;
        ((float4*)out)[p * PLANE_F4 + node * 4 + q] =
            make_float4(v.x * s, v.y * s, v.z * s, v.w * s);
    }
}

// ---------------------------------------------------------------------------
// 6) Feature-sliced SpMM (unchanged).
// ---------------------------------------------------------------------------
__global__ __launch_bounds__(256) void spmm_k(const float* __restrict__ x,   // sliced
                                              const int* __restrict__ row_ptr,
                                              const unsigned short* __restrict__ col,
                                              const float* __restrict__ nd,
                                              float* __restrict__ out) {     // sliced
    int b = blockIdx.x;
    int slice = b & 7;
    int node = (b >> 3) * 64 + (threadIdx.x >> 2);
    if (node >= N_NODES) return;
    int q = threadIdx.x & 3;
    int s = row_ptr[node];
    int e = row_ptr[node + 1];
    const float4* xp = (const float4*)x + slice * PLANE_F4;
    float4 a0 = make_float4(0.f, 0.f, 0.f, 0.f);
    float4 a1 = make_float4(0.f, 0.f, 0.f, 0.f);
    int i = s;
    for (; i + 4 <= e; i += 4) {
        int c0 = col[i], c1 = col[i + 1], c2 = col[i + 2], c3 = col[i + 3];
        float4 h0 = xp[c0 * 4 + q];
        float4 h1 = xp[c1 * 4 + q];
        float4 h2 = xp[c2 * 4 + q];
        float4 h3 = xp[c3 * 4 + q];
        a0.x += h0.x; a0.y += h0.y; a0.z += h0.z; a0.w += h0.w;
        a1.x += h1.x; a1.y += h1.y; a1.z += h1.z; a1.w += h1.w;
        a0.x += h2.x; a0.y += h2.y; a0.z += h2.z; a0.w += h2.w;
        a1.x += h3.x; a1.y += h3.y; a1.z += h3.z; a1.w += h3.w;
    }
    for (; i < e; i++) {
        float4 hv = xp[col[i] * 4 + q];
        a0.x += hv.x; a0.y += hv.y; a0.z += hv.z; a0.w += hv.w;
    }
    float ndv = nd[node];
    ((float4*)out)[slice * PLANE_F4 + node * 4 + q] =
        make_float4((a0.x + a1.x) * ndv, (a0.y + a1.y) * ndv,
                    (a0.z + a1.z) * ndv, (a0.w + a1.w) * ndv);
}

// ---------------------------------------------------------------------------
// 7) GEMM + bias + ReLU (structure unchanged from round 2; ns -> out_deg).
//    MODE 0: out = odeg^-1/2 * relu(A@W+b), SLICED. MODE 1: normal layout.
// ---------------------------------------------------------------------------
template <int MODE>
__global__ __launch_bounds__(512) void gemm_relu_k(const float* __restrict__ A,  // sliced
                                                   const float* __restrict__ W,
                                                   const float* __restrict__ bias,
                                                   const int* __restrict__ odeg,
                                                   float* __restrict__ out) {
    __shared__ float As_t[128 * 256];   // 128 KB: [k][r]
    int tid = threadIdx.x;
    int row0 = blockIdx.x * 256;
    const float4* A4 = (const float4*)A;

    #pragma unroll
    for (int it = 0; it < 16; it++) {
        int linear = it * 512 + tid;       // 0..8191 float4s
        int p = linear >> 10;              // plane 0..7
        int rem = linear & 1023;
        int r = rem >> 2;                  // local row 0..255
        int q = rem & 3;                   // float4 within 16-float slice
        int row = row0 + r;
        float4 a = (row < N_NODES) ? A4[p * PLANE_F4 + row * 4 + q]
                                   : make_float4(0.f, 0.f, 0.f, 0.f);
        int kb = p * 16 + q * 4;
        As_t[(kb + 0) * 256 + r] = a.x;
        As_t[(kb + 1) * 256 + r] = a.y;
        As_t[(kb + 2) * 256 + r] = a.z;
        As_t[(kb + 3) * 256 + r] = a.w;
    }
    __syncthreads();

    int tc = tid & 15;    // col group: cols tc*8 .. +8
    int tr = tid >> 4;    // 0..31 : rows tr*8 .. +8
    float acc[8][8];
    #pragma unroll
    for (int r = 0; r < 8; r++)
        #pragma unroll
        for (int c = 0; c < 8; c++) acc[r][c] = 0.f;

    const float4* W4 = (const float4*)W;
    #pragma unroll 2
    for (int k = 0; k < 128; k++) {
        float4 w0 = W4[k * 32 + tc * 2];
        float4 w1 = W4[k * 32 + tc * 2 + 1];
        float4 a0 = *(const float4*)(As_t + k * 256 + tr * 8);
        float4 a1 = *(const float4*)(As_t + k * 256 + tr * 8 + 4);
        float av[8] = {a0.x, a0.y, a0.z, a0.w, a1.x, a1.y, a1.z, a1.w};
        float wv[8] = {w0.x, w0.y, w0.z, w0.w, w1.x, w1.y, w1.z, w1.w};
        #pragma unroll
        for (int rr = 0; rr < 8; rr++)
            #pragma unroll
            for (int cc = 0; cc < 8; cc++)
                acc[rr][cc] = fmaf(av[rr], wv[cc], acc[rr][cc]);
    }

    float4 bv0 = ((const float4*)bias)[tc * 2];
    float4 bv1 = ((const float4*)bias)[tc * 2 + 1];
    #pragma unroll
    for (int rr = 0; rr < 8; rr++) {
        int row = row0 + tr * 8 + rr;
        if (row < N_NODES) {
            float4 o0, o1;
            o0.x = fmaxf(acc[rr][0] + bv0.x, 0.f);
            o0.y = fmaxf(acc[rr][1] + bv0.y, 0.f);
            o0.z = fmaxf(acc[rr][2] + bv0.z, 0.f);
            o0.w = fmaxf(acc[rr][3] + bv0.w, 0.f);
            o1.x = fmaxf(acc[rr][4] + bv1.x, 0.f);
            o1.y = fmaxf(acc[rr][5] + bv1.y, 0.f);
            o1.z = fmaxf(acc[rr][6] + bv1.z, 0.f);
            o1.w = fmaxf(acc[rr][7] + bv1.w, 0.f);
            if (MODE == 0) {
                int od = odeg[row];
                float s = 1.0f / sqrtf((float)(od > 1 ? od : 1));
                o0.x *= s; o0.y *= s; o0.z *= s; o0.w *= s;
                o1.x *= s; o1.y *= s; o1.z *= s; o1.w *= s;
                int p = tc >> 1;
                int q0 = (tc & 1) * 2;
                ((float4*)out)[p * PLANE_F4 + row * 4 + q0] = o0;
                ((float4*)out)[p * PLANE_F4 + row * 4 + q0 + 1] = o1;
            } else {
                ((float4*)out)[row * 32 + tc * 2] = o0;
                ((float4*)out)[row * 32 + tc * 2 + 1] = o1;
            }
        }
    }
}

// ---------------------------------------------------------------------------
// 8) Fused projection + readout (unchanged).
// ---------------------------------------------------------------------------
__global__ __launch_bounds__(256) void proj_readout_k(const float* __restrict__ h,
                                                      const int* __restrict__ gid,
                                                      const float* __restrict__ Wm,
                                                      float* __restrict__ hgp,
                                                      int* __restrict__ gcnt) {
    __shared__ float Wmt[10 * 144];
    int tid = threadIdx.x;
    for (int i = tid; i < 1280; i += 256) {
        int k = i / 10, o = i % 10;
        Wmt[o * 144 + k + 4 * (k >> 5)] = Wm[i];
    }
    __syncthreads();

    int v = blockIdx.x * 64 + (tid >> 2);
    int quarter = tid & 3;
    int lane = tid & 63;

    float acc[D_OUT];
    #pragma unroll
    for (int o = 0; o < D_OUT; o++) acc[o] = 0.f;
    int g = -1;
    int cnt = 0;
    if (v < N_NODES) {
        g = gid[v];
        cnt = (quarter == 0) ? 1 : 0;
        const float4* h4 = (const float4*)h + v * 32 + quarter * 8;
        const float* wbase = Wmt + quarter * 36;
        #pragma unroll
        for (int kk = 0; kk < 8; kk++) {
            float4 hv = h4[kk];
            #pragma unroll
            for (int o = 0; o < D_OUT; o++) {
                float4 w = *(const float4*)(wbase + o * 144 + kk * 4);
                acc[o] += hv.x * w.x + hv.y * w.y + hv.z * w.z + hv.w * w.w;
            }
        }
    }

    #pragma unroll
    for (int d = 1; d < 64; d <<= 1) {
        int gp = __shfl_up(g, d, 64);
        int cp = __shfl_up(cnt, d, 64);
        bool take = (lane >= d) && (gp == g);
        #pragma unroll
        for (int o = 0; o < D_OUT; o++) {
            float ap = __shfl_up(acc[o], d, 64);
            if (take) acc[o] += ap;
        }
        if (take) cnt += cp;
    }
    int gn = __shfl_down(g, 1, 64);
    bool tail = (lane == 63) || (gn != g);
    if (tail && g >= 0) {
        #pragma unroll
        for (int o = 0; o < D_OUT; o++) atomicAdd(&hgp[g * D_OUT + o], acc[o]);
        if (cnt > 0) atomicAdd(&gcnt[g], cnt);
    }
}

// ---------------------------------------------------------------------------
// 9) Final: logits = hgp/cnt + bm ; log_softmax over axis 0 (graphs)
// ---------------------------------------------------------------------------
__global__ __launch_bounds__(512) void final_k(const float* __restrict__ hgp,
                                               const int* __restrict__ gcnt,
                                               const float* __restrict__ bm,
                                               float* __restrict__ out) {
    __shared__ float lg[N_GRAPHS * D_OUT];
    __shared__ float colm[D_OUT], colls[D_OUT];
    int tid = threadIdx.x;
    if (tid < N_GRAPHS * D_OUT) {
        int g = tid / D_OUT, o = tid % D_OUT;
        float c = (float)gcnt[g];
        lg[tid] = hgp[tid] / (c > 1.f ? c : 1.f) + bm[o];
    }
    __syncthreads();
    if (tid < D_OUT) {
        float m = -1e30f;
        for (int g = 0; g < N_GRAPHS; g++) m = fmaxf(m, lg[g * D_OUT + tid]);
        float s = 0.f;
        for (int g = 0; g < N_GRAPHS; g++) s += expf(lg[g * D_OUT + tid] - m);
        colm[tid] = m; colls[tid] = logf(s);
    }
    __syncthreads();
    if (tid < N_GRAPHS * D_OUT) {
        int o = tid % D_OUT;
        out[tid] = lg[tid] - colm[o] - colls[o];
    }
}

// ---------------------------------------------------------------------------
// Launch. packed[] aliases bufB head (dead before spmm#1 writes bufB).
// Total footprint 53.6 MB.
// ---------------------------------------------------------------------------
extern "C" void kernel_launch(void* const* d_in, const int* in_sizes, int n_in,
                              void* d_out, int out_size, void* d_ws, size_t ws_size,
                              hipStream_t stream) {
    const float* h_in = (const float*)d_in[0];
    const int*   src  = (const int*)d_in[1];
    const int*   dst  = (const int*)d_in[2];
    const int*   gid  = (const int*)d_in[3];
    const float* W1 = (const float*)d_in[4];  const float* b1 = (const float*)d_in[5];
    const float* W2 = (const float*)d_in[6];  const float* b2 = (const float*)d_in[7];
    const float* W3 = (const float*)d_in[8];  const float* b3 = (const float*)d_in[9];
    const float* Wm = (const float*)d_in[10]; const float* bm = (const float*)d_in[11];

    char* ws = (char*)d_ws;
    int*            row_ptr = (int*)(ws + 0);                     // 50001 ints (pad 200,032)
    unsigned short* col16   = (unsigned short*)(ws + 200032);     // 1,600,000 B
    int*            out_deg = (int*)(ws + 1800032);               // 200,000 B
    float*          nd      = (float*)(ws + 2000032);             // 200,000 B
    int*            gcnt    = (int*)(ws + 2200032);               // 256 B
    float*          hgp     = (float*)(ws + 2200288);             // 2,048 B
    int*            gh      = (int*)(ws + 2202336);               // 38416*4 = 153,664 B
    float*          bufA    = (float*)(ws + 2356000);             // 25.6 MB
    float*          bufB    = (float*)(ws + 27956000);            // 25.6 MB -> 53,556,000
    unsigned int*   packed  = (unsigned int*)bufB;                // 3.2 MB alias

    hipMemsetAsync(out_deg, 0, 200000, stream);
    hipMemsetAsync(gcnt, 0, 2304, stream);          // gcnt + hgp

    part_hist_src<<<NBLK, 256, 0, stream>>>(src, dst, gh, out_deg);
    part_scan<<<1, 1024, 0, stream>>>(gh);
    part_scatter<<<NBLK, 256, 0, stream>>>(src, dst, gh, packed);
    bucket_csr<<<NB, 256, 0, stream>>>(packed, gh, col16, row_ptr, nd);
    prescale_k<<<6250, 256, 0, stream>>>(h_in, out_deg, bufA);

    spmm_k<<<6256, 256, 0, stream>>>(bufA, row_ptr, col16, nd, bufB);
    gemm_relu_k<0><<<196, 512, 0, stream>>>(bufB, W1, b1, out_deg, bufA);
    spmm_k<<<6256, 256, 0, stream>>>(bufA, row_ptr, col16, nd, bufB);
    gemm_relu_k<0><<<196, 512, 0, stream>>>(bufB, W2, b2, out_deg, bufA);
    spmm_k<<<6256, 256, 0, stream>>>(bufA, row_ptr, col16, nd, bufB);
    gemm_relu_k<1><<<196, 512, 0, stream>>>(bufB, W3, b3, out_deg, bufA);

    proj_readout_k<<<782, 256, 0, stream>>>(bufA, gid, Wm, hgp, gcnt);
    final_k<<<1, 512, 0, stream>>>(hgp, gcnt, bm, (float*)d_out);
}